// Round 12
// baseline (728.884 us; speedup 1.0000x reference)
//
#include <hip/hip_runtime.h>

// ATTRIBUTION ROUND: fwd/mix/inv launched with grid.z=3 (idempotent duplicate
// work) so each rises above the harness's ~155us poison-fill dispatches and
// appears in the rocprof top-5 with full counters. dur_us ~3x this round.
//
// QuantizedSpectralConv: B=16, CIN=COUT=64, H=W=256, modes 64x64.
// X layout: [r][i][b][p][c]; Y: packed bf16 (Yr | Yi<<16).

#define HW    256
#define NCIN  64
#define NCOUT 64
#define NB    16
#define R0    96
#define C0    32

typedef __bf16 bf16x2 __attribute__((ext_vector_type(2)));
typedef __bf16 bf16x8 __attribute__((ext_vector_type(8)));
typedef float  f32x4  __attribute__((ext_vector_type(4)));

__device__ __forceinline__ unsigned short f2bf(float f) {
    __bf16 h = (__bf16)f;
    return __builtin_bit_cast(unsigned short, h);
}
__device__ __forceinline__ unsigned pk2(float a, float b) {
    bf16x2 v;
    v.x = (__bf16)a;
    v.y = (__bf16)b;
    return __builtin_bit_cast(unsigned, v);
}
__device__ __forceinline__ bf16x8 ld_frag_g(const unsigned short* p) {
    return __builtin_bit_cast(bf16x8, *(const uint4*)p);
}
__device__ __forceinline__ void gload_lds16(const unsigned short* g, unsigned short* l) {
    __builtin_amdgcn_global_load_lds(
        (const __attribute__((address_space(1))) unsigned int*)g,
        (__attribute__((address_space(3))) unsigned int*)l, 16, 0, 0);
}
__device__ __forceinline__ void gload_lds16f(const float* g, float* l) {
    __builtin_amdgcn_global_load_lds(
        (const __attribute__((address_space(1))) unsigned int*)g,
        (__attribute__((address_space(3))) unsigned int*)l, 16, 0, 0);
}

// ---------------- inverse-stage tables ----------------
__global__ void build_tables2(unsigned short* __restrict__ A1tab,
                              unsigned short* __restrict__ B2T) {
    int idx = blockIdx.x * 256 + threadIdx.x;   // 0..32767
    int h = idx >> 7;
    int k = idx & 127;
    int kk = k & 63;
    const float TPO = 0.0245436926061702596754f;
    float s, c;
    int m1 = (((R0 + kk) * h) & 255);
    sincosf((float)m1 * TPO, &s, &c);
    A1tab[idx] = f2bf(k < 64 ? c : s);
    int m2 = (((C0 + kk) * h) & 255);
    sincosf((float)m2 * TPO, &s, &c);
    B2T[idx] = f2bf(k < 64 ? c : -s);
}

// ---------------- forward-stage tables ----------------
__global__ void build_fwd_tables(unsigned short* __restrict__ B1fT,
                                 unsigned short* __restrict__ A2f) {
    int idx = blockIdx.x * 256 + threadIdx.x;   // 0..98303
    const float TPO = 0.0245436926061702596754f;
    float s, c;
    if (idx < 32768) {
        int cc = idx >> 8, w = idx & 255;
        int m = (((C0 + (cc & 63)) * w) & 255);
        sincosf((float)m * TPO, &s, &c);
        int sidx = (cc << 8) | (w ^ ((cc & 7) << 3));   // pre-swizzled slot
        B1fT[sidx] = f2bf(cc < 64 ? c : -s);
    } else {
        int j = idx - 32768;
        int mr = j >> 9, k = j & 511;
        int m = (((R0 + (mr & 63)) * (k & 255)) & 255);
        sincosf((float)m * TPO, &s, &c);
        float v = (mr < 64) ? ((k < 256) ? c : s)
                            : ((k < 256) ? -s : c);
        A2f[j] = f2bf(v);
    }
}

// ---------------- forward: 4-wave block per (b,i) image, DMA-piped x ----------------
__global__ __launch_bounds__(256, 1) void fwd_mfma(
        const float*          __restrict__ x,
        const unsigned short* __restrict__ B1fT,
        const unsigned short* __restrict__ A2f,
        float*                __restrict__ Xout) {
    __shared__ __align__(16) unsigned short smem[65536];   // 128 KB
    float* xbufF = (float*)(smem + 32768);                 // 16384 dwords
    int bi = blockIdx.x;
    const float* xim = x + (size_t)bi * 65536;
    int t = threadIdx.x, lane = t & 63, wv = t >> 6;       // wv 0..3
    int g = lane >> 4, lr = lane & 15;

    #pragma unroll
    for (int i = 0; i < 16; ++i)
        gload_lds16(B1fT + i * 2048 + t * 8, &smem[i * 2048 + wv * 512]);

    {
        int rbase = (lane >> 3);
        int c4    = (lane & 7) ^ (lane >> 3);
        #pragma unroll
        for (int i = 0; i < 8; ++i) {
            int gidx = wv * 8 + i;
            gload_lds16f(xim + (gidx * 8 + rbase) * 256 + c4 * 4,
                         xbufF + gidx * 256);
        }
    }
    __syncthreads();

    f32x4 acc[4][8];
    #pragma unroll
    for (int mf = 0; mf < 4; ++mf)
        #pragma unroll
        for (int nf = 0; nf < 8; ++nf) acc[mf][nf] = (f32x4)0.0f;

    for (int ch = 0; ch < 8; ++ch) {
        const int cur = ch & 1;
        float* xb = xbufF + cur * 8192;
        if (ch < 7) {
            float* xn = xbufF + (cur ^ 1) * 8192;
            int rbase = (lane >> 3);
            int c4    = (lane & 7) ^ (lane >> 3);
            const float* src = xim + (ch + 1) * 32;
            #pragma unroll
            for (int i = 0; i < 8; ++i) {
                int gidx = wv * 8 + i;
                gload_lds16f(src + (gidx * 8 + rbase) * 256 + c4 * 4,
                             xn + gidx * 256);
            }
        }
        int k0 = ch * 32 + g * 8;
        bf16x8 b[8];
        #pragma unroll
        for (int nf = 0; nf < 8; ++nf) {
            int n = nf * 16 + lr;
            b[nf] = __builtin_bit_cast(bf16x8,
                      *(const uint4*)&smem[n * 256 + (k0 ^ ((n & 7) << 3))]);
        }
        bf16x8 a[4];
        #pragma unroll
        for (int mf = 0; mf < 4; ++mf) {
            int h  = wv * 64 + mf * 16 + lr;
            int s0 = (2 * g)     ^ (h & 7);
            int s1 = (2 * g + 1) ^ (h & 7);
            float4 p0 = *(const float4*)&xb[h * 32 + s0 * 4];
            float4 p1 = *(const float4*)&xb[h * 32 + s1 * 4];
            uint4 pk;
            pk.x = pk2(p0.x, p0.y); pk.y = pk2(p0.z, p0.w);
            pk.z = pk2(p1.x, p1.y); pk.w = pk2(p1.z, p1.w);
            a[mf] = __builtin_bit_cast(bf16x8, pk);
        }
        #pragma unroll
        for (int mf = 0; mf < 4; ++mf)
            #pragma unroll
            for (int nf = 0; nf < 8; ++nf)
                acc[mf][nf] = __builtin_amdgcn_mfma_f32_16x16x32_bf16(
                                  a[mf], b[nf], acc[mf][nf], 0, 0, 0);
        __syncthreads();
    }

    unsigned short* bop = smem + 32768;
    #pragma unroll
    for (int mf = 0; mf < 4; ++mf)
        #pragma unroll
        for (int nf = 0; nf < 8; ++nf) {
            int cl  = nf * 16 + lr;
            int col = cl & 63;
            int h0  = wv * 64 + mf * 16 + g * 4;
            int kk0 = (cl < 64) ? h0 : (256 + h0);
            uint2 pk;
            pk.x = pk2(acc[mf][nf][0], acc[mf][nf][1]);
            pk.y = pk2(acc[mf][nf][2], acc[mf][nf][3]);
            *(uint2*)&bop[col * 512 + (kk0 ^ ((col & 7) << 3))] = pk;
        }
    __syncthreads();

    f32x4 acc2[2][4];
    #pragma unroll
    for (int mf = 0; mf < 2; ++mf)
        #pragma unroll
        for (int nf = 0; nf < 4; ++nf) acc2[mf][nf] = (f32x4)0.0f;
    #pragma unroll
    for (int ks = 0; ks < 16; ++ks) {
        int k0 = ks * 32 + g * 8;
        bf16x8 a2[2], b2[4];
        #pragma unroll
        for (int mf = 0; mf < 2; ++mf) {
            int m = wv * 32 + mf * 16 + lr;
            a2[mf] = ld_frag_g(A2f + m * 512 + k0);
        }
        #pragma unroll
        for (int nf = 0; nf < 4; ++nf) {
            int c = nf * 16 + lr;
            b2[nf] = __builtin_bit_cast(bf16x8,
                       *(const uint4*)&bop[c * 512 + (k0 ^ ((c & 7) << 3))]);
        }
        #pragma unroll
        for (int mf = 0; mf < 2; ++mf)
            #pragma unroll
            for (int nf = 0; nf < 4; ++nf)
                acc2[mf][nf] = __builtin_amdgcn_mfma_f32_16x16x32_bf16(
                                   a2[mf], b2[nf], acc2[mf][nf], 0, 0, 0);
    }
    {
        int bb = bi >> 6, ii = bi & 63;
        #pragma unroll
        for (int mf = 0; mf < 2; ++mf)
            #pragma unroll
            for (int nf = 0; nf < 4; ++nf)
                #pragma unroll
                for (int rg = 0; rg < 4; ++rg) {
                    int m = wv * 32 + mf * 16 + g * 4 + rg;
                    int c = nf * 16 + lr;
                    int r = m & 63, p = m >> 6;
                    Xout[(size_t)r * 131072 + ii * 2048 + bb * 128 + p * 64 + c]
                        = acc2[mf][nf][rg];
                }
    }
}

// ---------------- stage C: streaming channel mix ----------------
__global__ __launch_bounds__(256) void mix_kernel(
        const float* __restrict__ X,      // [r][i][b][p][c]
        const int*   __restrict__ q_real,
        const int*   __restrict__ q_imag,
        const float* __restrict__ s_r, const float* __restrict__ m_r,
        const float* __restrict__ s_i, const float* __restrict__ m_i,
        unsigned*    __restrict__ Yb) {
    int rr = blockIdx.x;
    int ot = blockIdx.y;
    int t  = threadIdx.x, lane = t & 63, wv = t >> 6;
    int cp = t & 31;
    int oq = t >> 5;
    int o  = ot * 8 + oq;
    int c0 = cp * 2;
    float sr = *s_r, mr = *m_r, si = *s_i, mi = *m_i;

    __shared__ __align__(16) float sh[2][2048];
    const float* xsl = X + (size_t)rr * 131072;

    const int* qrp = q_real + (size_t)o * 4096 + rr * 64 + c0;
    const int* qip = q_imag + (size_t)o * 4096 + rr * 64 + c0;

    float Yr0[16], Yi0[16], Yr1[16], Yi1[16];
    #pragma unroll
    for (int b = 0; b < 16; ++b) { Yr0[b] = 0.f; Yi0[b] = 0.f; Yr1[b] = 0.f; Yi1[b] = 0.f; }

    int2 wqr[2], wqi[2];
    wqr[0] = *(const int2*)(qrp);
    wqi[0] = *(const int2*)(qip);
    wqr[1] = *(const int2*)(qrp + 262144);
    wqi[1] = *(const int2*)(qip + 262144);
    {
        const float* src = xsl + wv * 512;
        gload_lds16f(src + lane * 4,       &sh[0][wv * 512]);
        gload_lds16f(src + 256 + lane * 4, &sh[0][wv * 512 + 256]);
    }
    __syncthreads();

    #pragma unroll 2
    for (int i = 0; i < 64; ++i) {
        const int cur = i & 1;
        if (i < 63) {
            const float* src = xsl + (i + 1) * 2048 + wv * 512;
            gload_lds16f(src + lane * 4,       &sh[cur ^ 1][wv * 512]);
            gload_lds16f(src + 256 + lane * 4, &sh[cur ^ 1][wv * 512 + 256]);
        }
        float wr0 = (float)(wqr[cur].x + 127) * sr + mr;
        float wr1 = (float)(wqr[cur].y + 127) * sr + mr;
        float wi0 = (float)(wqi[cur].x + 127) * si + mi;
        float wi1 = (float)(wqi[cur].y + 127) * si + mi;
        if (i < 62) {
            wqr[cur] = *(const int2*)(qrp + (size_t)(i + 2) * 262144);
            wqi[cur] = *(const int2*)(qip + (size_t)(i + 2) * 262144);
        }
        #pragma unroll
        for (int b = 0; b < 16; ++b) {
            float2 xr = *(const float2*)&sh[cur][b * 128 + c0];
            float2 xi = *(const float2*)&sh[cur][b * 128 + 64 + c0];
            Yr0[b] += xr.x * wr0 - xi.x * wi0;
            Yi0[b] += xr.x * wi0 + xi.x * wr0;
            Yr1[b] += xr.y * wr1 - xi.y * wi1;
            Yi1[b] += xr.y * wi1 + xi.y * wr1;
        }
        if (i < 63) __syncthreads();
    }

    #pragma unroll
    for (int b = 0; b < 16; ++b) {
        uint2 v;
        v.x = pk2(Yr0[b], Yi0[b]);
        v.y = pk2(Yr1[b], Yi1[b]);
        *(uint2*)&Yb[(size_t)(b * NCOUT + o) * 4096 + rr * 64 + c0] = v;
    }
}

// ---------------- inverse: two bf16 MFMA GEMMs per (b,o) image ----------------
__global__ __launch_bounds__(256, 2) void inv_mfma(
        const unsigned*       __restrict__ Y,      // packed bf16 (Yr | Yi<<16)
        const unsigned short* __restrict__ A1tab,
        const unsigned short* __restrict__ B2T,
        const int*            __restrict__ q_bias,
        const float* __restrict__ b_s, const float* __restrict__ b_m,
        float*                __restrict__ out) {
    __shared__ __align__(16) unsigned short smem[32768];
    int bo   = blockIdx.x;
    int t    = threadIdx.x;
    int lane = t & 63;
    int wv   = t >> 6;
    int g    = lane >> 4;
    int lr   = lane & 15;
    float bias = ((float)q_bias[bo & 63] + 127.0f) * (*b_s) + (*b_m);

    {
        const unsigned* Yp = Y + (size_t)bo * 4096;
        uint4 y0 = *(const uint4*)(Yp + t * 16);
        uint4 y1 = *(const uint4*)(Yp + t * 16 + 4);
        uint4 y2 = *(const uint4*)(Yp + t * 16 + 8);
        uint4 y3 = *(const uint4*)(Yp + t * 16 + 12);
        unsigned ys[16] = {y0.x, y0.y, y0.z, y0.w, y1.x, y1.y, y1.z, y1.w,
                           y2.x, y2.y, y2.z, y2.w, y3.x, y3.y, y3.z, y3.w};
        int r  = t >> 2;
        int cb = (t & 3) * 16;
        #pragma unroll
        for (int j = 0; j < 16; ++j) {
            int c = cb + j;
            unsigned y = ys[j];
            unsigned short yr  = (unsigned short)(y & 0xFFFFu);
            unsigned short yi  = (unsigned short)(y >> 16);
            unsigned short nyi = (unsigned short)(yi ^ 0x8000u);
            int sw = (c & 7) << 3;
            smem[c * 128        + ((r)      ^ sw)] = yr;
            smem[c * 128        + ((64 + r) ^ sw)] = nyi;
            smem[(64 + c) * 128 + ((r)      ^ sw)] = yi;
            smem[(64 + c) * 128 + ((64 + r) ^ sw)] = yr;
        }
    }
    __syncthreads();

    f32x4 acc[4][8];
    #pragma unroll
    for (int mf = 0; mf < 4; ++mf)
        #pragma unroll
        for (int nf = 0; nf < 8; ++nf) acc[mf][nf] = (f32x4)0.0f;

    #pragma unroll
    for (int ks = 0; ks < 4; ++ks) {
        int k0 = ks * 32 + g * 8;
        bf16x8 a[4], b[8];
        #pragma unroll
        for (int mf = 0; mf < 4; ++mf) {
            int h = wv * 64 + mf * 16 + lr;
            a[mf] = ld_frag_g(A1tab + h * 128 + k0);
        }
        #pragma unroll
        for (int nf = 0; nf < 8; ++nf) {
            int n = nf * 16 + lr;
            b[nf] = ld_frag_g(&smem[n * 128 + (k0 ^ ((n & 7) << 3))]);
        }
        #pragma unroll
        for (int mf = 0; mf < 4; ++mf)
            #pragma unroll
            for (int nf = 0; nf < 8; ++nf)
                acc[mf][nf] = __builtin_amdgcn_mfma_f32_16x16x32_bf16(
                                  a[mf], b[nf], acc[mf][nf], 0, 0, 0);
    }
    __syncthreads();

    #pragma unroll
    for (int mf = 0; mf < 4; ++mf)
        #pragma unroll
        for (int nf = 0; nf < 8; ++nf)
            #pragma unroll
            for (int rg = 0; rg < 4; ++rg) {
                int h = wv * 64 + mf * 16 + g * 4 + rg;
                int k = nf * 16 + lr;
                smem[h * 128 + (k ^ ((h & 7) << 3))] = f2bf(acc[mf][nf][rg]);
            }
    __syncthreads();

    const float scale = 2.0f / 65536.0f;
    float* outp = out + (size_t)bo * 65536;
    #pragma unroll
    for (int nh = 0; nh < 2; ++nh) {
        f32x4 acc2[4][8];
        #pragma unroll
        for (int mf = 0; mf < 4; ++mf)
            #pragma unroll
            for (int nf = 0; nf < 8; ++nf) acc2[mf][nf] = (f32x4)0.0f;

        #pragma unroll
        for (int ks = 0; ks < 4; ++ks) {
            int k0 = ks * 32 + g * 8;
            bf16x8 a[4], b[8];
            #pragma unroll
            for (int mf = 0; mf < 4; ++mf) {
                int h = wv * 64 + mf * 16 + lr;
                a[mf] = ld_frag_g(&smem[h * 128 + (k0 ^ ((h & 7) << 3))]);
            }
            #pragma unroll
            for (int nf = 0; nf < 8; ++nf) {
                int w = nh * 128 + nf * 16 + lr;
                b[nf] = ld_frag_g(B2T + w * 128 + k0);
            }
            #pragma unroll
            for (int mf = 0; mf < 4; ++mf)
                #pragma unroll
                for (int nf = 0; nf < 8; ++nf)
                    acc2[mf][nf] = __builtin_amdgcn_mfma_f32_16x16x32_bf16(
                                       a[mf], b[nf], acc2[mf][nf], 0, 0, 0);
        }
        #pragma unroll
        for (int mf = 0; mf < 4; ++mf)
            #pragma unroll
            for (int rg = 0; rg < 4; ++rg) {
                int h = wv * 64 + mf * 16 + g * 4 + rg;
                float* row = outp + h * 256 + nh * 128 + lr;
                #pragma unroll
                for (int nf = 0; nf < 8; ++nf)
                    row[nf * 16] = acc2[mf][nf][rg] * scale + bias;
            }
    }
}

extern "C" void kernel_launch(void* const* d_in, const int* in_sizes, int n_in,
                              void* d_out, int out_size, void* d_ws, size_t ws_size,
                              hipStream_t stream) {
    const float* x          = (const float*)d_in[0];
    const int*   q_real     = (const int*)  d_in[1];
    const int*   q_imag     = (const int*)  d_in[2];
    const int*   q_bias     = (const int*)  d_in[3];
    const float* scale_real = (const float*)d_in[4];
    const float* min_real   = (const float*)d_in[5];
    const float* scale_imag = (const float*)d_in[6];
    const float* min_imag   = (const float*)d_in[7];
    const float* b_scale    = (const float*)d_in[8];
    const float* b_min      = (const float*)d_in[9];
    float* out = (float*)d_out;

    float* ws = (float*)d_ws;
    unsigned short* A1tab = (unsigned short*)(ws);
    unsigned short* B2T   = (unsigned short*)(ws + 16384);
    unsigned short* B1fT  = (unsigned short*)(ws + 32768);
    unsigned short* A2f   = (unsigned short*)(ws + 49152);
    float*          Xws   = (float*)   (ws + 81920);
    unsigned*       Ybws  = (unsigned*)(ws + 81920 + 8388608);

    build_tables2<<<128, 256, 0, stream>>>(A1tab, B2T);
    build_fwd_tables<<<384, 256, 0, stream>>>(B1fT, A2f);
    // ATTRIBUTION: z=3 duplicates (idempotent) to surface each kernel in top-5
    fwd_mfma<<<dim3(NB * NCIN, 1, 3), 256, 0, stream>>>(x, B1fT, A2f, Xws);
    mix_kernel<<<dim3(64, 8, 3), 256, 0, stream>>>(Xws, q_real, q_imag,
                                                   scale_real, min_real,
                                                   scale_imag, min_imag, Ybws);
    inv_mfma<<<dim3(NB * NCOUT, 1, 3), 256, 0, stream>>>(Ybws, A1tab, B2T,
                                                         q_bias, b_scale, b_min, out);
}

// Round 13
// 273.697 us; speedup vs baseline: 2.6631x; 2.6631x over previous
//
#include <hip/hip_runtime.h>

// QuantizedSpectralConv: B=16, CIN=COUT=64, H=W=256, modes 64x64.
// rows r = 96..159, cols c = 32..95.
// X layout: [r][i][b][p][c]; Y: packed bf16 (Yr | Yi<<16).
// fwd: 8-wave (512-thr) blocks, 64 KB LDS union (B1fT -> Bop) => 2 blocks/CU,
//      4 waves/SIMD (R12 attribution: fwd was 1 wave/SIMD latency-bound).

#define HW    256
#define NCIN  64
#define NCOUT 64
#define NB    16
#define R0    96
#define C0    32

typedef __bf16 bf16x2 __attribute__((ext_vector_type(2)));
typedef __bf16 bf16x8 __attribute__((ext_vector_type(8)));
typedef float  f32x4  __attribute__((ext_vector_type(4)));

__device__ __forceinline__ unsigned short f2bf(float f) {
    __bf16 h = (__bf16)f;
    return __builtin_bit_cast(unsigned short, h);
}
__device__ __forceinline__ unsigned pk2(float a, float b) {
    bf16x2 v;
    v.x = (__bf16)a;
    v.y = (__bf16)b;
    return __builtin_bit_cast(unsigned, v);
}
__device__ __forceinline__ bf16x8 ld_frag_g(const unsigned short* p) {
    return __builtin_bit_cast(bf16x8, *(const uint4*)p);
}
__device__ __forceinline__ void gload_lds16(const unsigned short* g, unsigned short* l) {
    __builtin_amdgcn_global_load_lds(
        (const __attribute__((address_space(1))) unsigned int*)g,
        (__attribute__((address_space(3))) unsigned int*)l, 16, 0, 0);
}
__device__ __forceinline__ void gload_lds16f(const float* g, float* l) {
    __builtin_amdgcn_global_load_lds(
        (const __attribute__((address_space(1))) unsigned int*)g,
        (__attribute__((address_space(3))) unsigned int*)l, 16, 0, 0);
}

// ---------------- all trig tables, one launch, fast sincos ----------------
// A1tab[h][k] [256][128]: k<64 cos(2pi(R0+k)h/256), k>=64 sin(...)
// B2T[w][k]  [256][128]: k<64 cos(2pi(C0+k)w/256), k>=64 -sin(...)
// B1fT pre-swizzled [128][256]: val(cc,w) at cc*256 + (w ^ ((cc&7)<<3))
// A2f [128][512]
__global__ void build_all_tables(unsigned short* __restrict__ A1tab,
                                 unsigned short* __restrict__ B2T,
                                 unsigned short* __restrict__ B1fT,
                                 unsigned short* __restrict__ A2f) {
    int idx = blockIdx.x * 256 + threadIdx.x;   // 0..131071
    const float TPO = 0.0245436926061702596754f;
    float s, c;
    if (idx < 32768) {
        int h = idx >> 7;
        int k = idx & 127;
        int kk = k & 63;
        __sincosf((float)(((R0 + kk) * h) & 255) * TPO, &s, &c);
        A1tab[idx] = f2bf(k < 64 ? c : s);
        __sincosf((float)(((C0 + kk) * h) & 255) * TPO, &s, &c);
        B2T[idx] = f2bf(k < 64 ? c : -s);
    } else if (idx < 65536) {
        int j = idx - 32768;
        int cc = j >> 8, w = j & 255;
        __sincosf((float)(((C0 + (cc & 63)) * w) & 255) * TPO, &s, &c);
        B1fT[(cc << 8) | (w ^ ((cc & 7) << 3))] = f2bf(cc < 64 ? c : -s);
    } else {
        int j = idx - 65536;
        int mr = j >> 9, k = j & 511;
        __sincosf((float)(((R0 + (mr & 63)) * (k & 255)) & 255) * TPO, &s, &c);
        float v = (mr < 64) ? ((k < 256) ? c : s)
                            : ((k < 256) ? -s : c);
        A2f[j] = f2bf(v);
    }
}

// ---------------- forward: 8-wave block per (b,i) image ----------------
// GEMM-A: T1cat[256h][128cl] = x * B1f. Wave w: rows w*32..+31 (2 mf frags).
//   x-frags direct from global (line-coalesced); B-frags from LDS (swizzled).
// GEMM-B: Xcat[128][64] = A2f[128][512] * Bop[512][64]; wave w -> m-frag w.
__global__ __launch_bounds__(512, 4) void fwd_mfma(
        const float*          __restrict__ x,
        const unsigned short* __restrict__ B1fT,
        const unsigned short* __restrict__ A2f,
        float*                __restrict__ Xout) {
    __shared__ __align__(16) unsigned short smem[32768];   // 64 KB union
    int bi = blockIdx.x;
    const float* xim = x + (size_t)bi * 65536;
    int t = threadIdx.x, lane = t & 63, wv = t >> 6;       // wv 0..7
    int g = lane >> 4, lr = lane & 15;

    // stage B1fT (pre-swizzled) -> LDS: 8 x 512thr x 16B = 64 KB
    #pragma unroll
    for (int i = 0; i < 8; ++i)
        gload_lds16(B1fT + i * 4096 + t * 8, &smem[i * 4096 + wv * 512]);

    const float* xrow[2];
    #pragma unroll
    for (int mf = 0; mf < 2; ++mf)
        xrow[mf] = xim + (wv * 32 + mf * 16 + lr) * 256 + g * 8;
    __syncthreads();   // B1fT resident

    // ---- GEMM-A ----
    f32x4 acc[2][8];
    #pragma unroll
    for (int mf = 0; mf < 2; ++mf)
        #pragma unroll
        for (int nf = 0; nf < 8; ++nf) acc[mf][nf] = (f32x4)0.0f;

    #pragma unroll
    for (int ks = 0; ks < 8; ++ks) {
        int k0 = ks * 32 + g * 8;
        bf16x8 a[2];
        #pragma unroll
        for (int mf = 0; mf < 2; ++mf) {
            float4 v0 = *(const float4*)(xrow[mf] + ks * 32);
            float4 v1 = *(const float4*)(xrow[mf] + ks * 32 + 4);
            uint4 pk;
            pk.x = pk2(v0.x, v0.y); pk.y = pk2(v0.z, v0.w);
            pk.z = pk2(v1.x, v1.y); pk.w = pk2(v1.z, v1.w);
            a[mf] = __builtin_bit_cast(bf16x8, pk);
        }
        #pragma unroll
        for (int half = 0; half < 2; ++half) {   // 4-wide b halves: VGPR pressure
            bf16x8 b[4];
            #pragma unroll
            for (int j = 0; j < 4; ++j) {
                int n = (half * 4 + j) * 16 + lr;
                b[j] = __builtin_bit_cast(bf16x8,
                         *(const uint4*)&smem[n * 256 + (k0 ^ ((n & 7) << 3))]);
            }
            #pragma unroll
            for (int mf = 0; mf < 2; ++mf)
                #pragma unroll
                for (int j = 0; j < 4; ++j)
                    acc[mf][half * 4 + j] = __builtin_amdgcn_mfma_f32_16x16x32_bf16(
                        a[mf], b[j], acc[mf][half * 4 + j], 0, 0, 0);
        }
    }
    __syncthreads();   // all B1fT reads done; smem becomes Bop[64][512]

    // ---- T1 -> Bop (bf16, swizzled); frag rows h0 = wv*32+mf*16+g*4 ----
    #pragma unroll
    for (int mf = 0; mf < 2; ++mf)
        #pragma unroll
        for (int nf = 0; nf < 8; ++nf) {
            int cl  = nf * 16 + lr;
            int col = cl & 63;
            int h0  = wv * 32 + mf * 16 + g * 4;
            int kk0 = (cl < 64) ? h0 : (256 + h0);
            uint2 pk;
            pk.x = pk2(acc[mf][nf][0], acc[mf][nf][1]);
            pk.y = pk2(acc[mf][nf][2], acc[mf][nf][3]);
            *(uint2*)&smem[col * 512 + (kk0 ^ ((col & 7) << 3))] = pk;
        }
    __syncthreads();

    // ---- GEMM-B: wave w -> m-frag w (rows wv*16..+15), all 4 c-frags ----
    f32x4 acc2[4];
    #pragma unroll
    for (int nf = 0; nf < 4; ++nf) acc2[nf] = (f32x4)0.0f;
    const unsigned short* a2row = A2f + (wv * 16 + lr) * 512;
    #pragma unroll
    for (int ks = 0; ks < 16; ++ks) {
        int k0 = ks * 32 + g * 8;
        bf16x8 a2 = ld_frag_g(a2row + k0);
        #pragma unroll
        for (int nf = 0; nf < 4; ++nf) {
            int c = nf * 16 + lr;
            bf16x8 b2 = __builtin_bit_cast(bf16x8,
                          *(const uint4*)&smem[c * 512 + (k0 ^ ((c & 7) << 3))]);
            acc2[nf] = __builtin_amdgcn_mfma_f32_16x16x32_bf16(a2, b2, acc2[nf], 0, 0, 0);
        }
    }
    // X layout [r][i][b][p][c]
    {
        int bb = bi >> 6, ii = bi & 63;
        #pragma unroll
        for (int nf = 0; nf < 4; ++nf)
            #pragma unroll
            for (int rg = 0; rg < 4; ++rg) {
                int m = wv * 16 + g * 4 + rg;
                int c = nf * 16 + lr;
                int r = m & 63, p = m >> 6;
                Xout[(size_t)r * 131072 + ii * 2048 + bb * 128 + p * 64 + c]
                    = acc2[nf][rg];
            }
    }
}

// ---------------- stage C: streaming channel mix (unchanged) ----------------
__global__ __launch_bounds__(256) void mix_kernel(
        const float* __restrict__ X,      // [r][i][b][p][c]
        const int*   __restrict__ q_real,
        const int*   __restrict__ q_imag,
        const float* __restrict__ s_r, const float* __restrict__ m_r,
        const float* __restrict__ s_i, const float* __restrict__ m_i,
        unsigned*    __restrict__ Yb) {
    int rr = blockIdx.x;
    int ot = blockIdx.y;
    int t  = threadIdx.x, lane = t & 63, wv = t >> 6;
    int cp = t & 31;
    int oq = t >> 5;
    int o  = ot * 8 + oq;
    int c0 = cp * 2;
    float sr = *s_r, mr = *m_r, si = *s_i, mi = *m_i;

    __shared__ __align__(16) float sh[2][2048];
    const float* xsl = X + (size_t)rr * 131072;

    const int* qrp = q_real + (size_t)o * 4096 + rr * 64 + c0;
    const int* qip = q_imag + (size_t)o * 4096 + rr * 64 + c0;

    float Yr0[16], Yi0[16], Yr1[16], Yi1[16];
    #pragma unroll
    for (int b = 0; b < 16; ++b) { Yr0[b] = 0.f; Yi0[b] = 0.f; Yr1[b] = 0.f; Yi1[b] = 0.f; }

    int2 wqr[2], wqi[2];
    wqr[0] = *(const int2*)(qrp);
    wqi[0] = *(const int2*)(qip);
    wqr[1] = *(const int2*)(qrp + 262144);
    wqi[1] = *(const int2*)(qip + 262144);
    {
        const float* src = xsl + wv * 512;
        gload_lds16f(src + lane * 4,       &sh[0][wv * 512]);
        gload_lds16f(src + 256 + lane * 4, &sh[0][wv * 512 + 256]);
    }
    __syncthreads();

    #pragma unroll 2
    for (int i = 0; i < 64; ++i) {
        const int cur = i & 1;
        if (i < 63) {
            const float* src = xsl + (i + 1) * 2048 + wv * 512;
            gload_lds16f(src + lane * 4,       &sh[cur ^ 1][wv * 512]);
            gload_lds16f(src + 256 + lane * 4, &sh[cur ^ 1][wv * 512 + 256]);
        }
        float wr0 = (float)(wqr[cur].x + 127) * sr + mr;
        float wr1 = (float)(wqr[cur].y + 127) * sr + mr;
        float wi0 = (float)(wqi[cur].x + 127) * si + mi;
        float wi1 = (float)(wqi[cur].y + 127) * si + mi;
        if (i < 62) {
            wqr[cur] = *(const int2*)(qrp + (size_t)(i + 2) * 262144);
            wqi[cur] = *(const int2*)(qip + (size_t)(i + 2) * 262144);
        }
        #pragma unroll
        for (int b = 0; b < 16; ++b) {
            float2 xr = *(const float2*)&sh[cur][b * 128 + c0];
            float2 xi = *(const float2*)&sh[cur][b * 128 + 64 + c0];
            Yr0[b] += xr.x * wr0 - xi.x * wi0;
            Yi0[b] += xr.x * wi0 + xi.x * wr0;
            Yr1[b] += xr.y * wr1 - xi.y * wi1;
            Yi1[b] += xr.y * wi1 + xi.y * wr1;
        }
        if (i < 63) __syncthreads();
    }

    #pragma unroll
    for (int b = 0; b < 16; ++b) {
        uint2 v;
        v.x = pk2(Yr0[b], Yi0[b]);
        v.y = pk2(Yr1[b], Yi1[b]);
        *(uint2*)&Yb[(size_t)(b * NCOUT + o) * 4096 + rr * 64 + c0] = v;
    }
}

// ---------------- inverse: two bf16 MFMA GEMMs per (b,o) image (unchanged) ----------------
__global__ __launch_bounds__(256, 2) void inv_mfma(
        const unsigned*       __restrict__ Y,      // packed bf16 (Yr | Yi<<16)
        const unsigned short* __restrict__ A1tab,
        const unsigned short* __restrict__ B2T,
        const int*            __restrict__ q_bias,
        const float* __restrict__ b_s, const float* __restrict__ b_m,
        float*                __restrict__ out) {
    __shared__ __align__(16) unsigned short smem[32768];
    int bo   = blockIdx.x;
    int t    = threadIdx.x;
    int lane = t & 63;
    int wv   = t >> 6;
    int g    = lane >> 4;
    int lr   = lane & 15;
    float bias = ((float)q_bias[bo & 63] + 127.0f) * (*b_s) + (*b_m);

    {
        const unsigned* Yp = Y + (size_t)bo * 4096;
        uint4 y0 = *(const uint4*)(Yp + t * 16);
        uint4 y1 = *(const uint4*)(Yp + t * 16 + 4);
        uint4 y2 = *(const uint4*)(Yp + t * 16 + 8);
        uint4 y3 = *(const uint4*)(Yp + t * 16 + 12);
        unsigned ys[16] = {y0.x, y0.y, y0.z, y0.w, y1.x, y1.y, y1.z, y1.w,
                           y2.x, y2.y, y2.z, y2.w, y3.x, y3.y, y3.z, y3.w};
        int r  = t >> 2;
        int cb = (t & 3) * 16;
        #pragma unroll
        for (int j = 0; j < 16; ++j) {
            int c = cb + j;
            unsigned y = ys[j];
            unsigned short yr  = (unsigned short)(y & 0xFFFFu);
            unsigned short yi  = (unsigned short)(y >> 16);
            unsigned short nyi = (unsigned short)(yi ^ 0x8000u);
            int sw = (c & 7) << 3;
            smem[c * 128        + ((r)      ^ sw)] = yr;
            smem[c * 128        + ((64 + r) ^ sw)] = nyi;
            smem[(64 + c) * 128 + ((r)      ^ sw)] = yi;
            smem[(64 + c) * 128 + ((64 + r) ^ sw)] = yr;
        }
    }
    __syncthreads();

    f32x4 acc[4][8];
    #pragma unroll
    for (int mf = 0; mf < 4; ++mf)
        #pragma unroll
        for (int nf = 0; nf < 8; ++nf) acc[mf][nf] = (f32x4)0.0f;

    #pragma unroll
    for (int ks = 0; ks < 4; ++ks) {
        int k0 = ks * 32 + g * 8;
        bf16x8 a[4], b[8];
        #pragma unroll
        for (int mf = 0; mf < 4; ++mf) {
            int h = wv * 64 + mf * 16 + lr;
            a[mf] = ld_frag_g(A1tab + h * 128 + k0);
        }
        #pragma unroll
        for (int nf = 0; nf < 8; ++nf) {
            int n = nf * 16 + lr;
            b[nf] = ld_frag_g(&smem[n * 128 + (k0 ^ ((n & 7) << 3))]);
        }
        #pragma unroll
        for (int mf = 0; mf < 4; ++mf)
            #pragma unroll
            for (int nf = 0; nf < 8; ++nf)
                acc[mf][nf] = __builtin_amdgcn_mfma_f32_16x16x32_bf16(
                                  a[mf], b[nf], acc[mf][nf], 0, 0, 0);
    }
    __syncthreads();

    #pragma unroll
    for (int mf = 0; mf < 4; ++mf)
        #pragma unroll
        for (int nf = 0; nf < 8; ++nf)
            #pragma unroll
            for (int rg = 0; rg < 4; ++rg) {
                int h = wv * 64 + mf * 16 + g * 4 + rg;
                int k = nf * 16 + lr;
                smem[h * 128 + (k ^ ((h & 7) << 3))] = f2bf(acc[mf][nf][rg]);
            }
    __syncthreads();

    const float scale = 2.0f / 65536.0f;
    float* outp = out + (size_t)bo * 65536;
    #pragma unroll
    for (int nh = 0; nh < 2; ++nh) {
        f32x4 acc2[4][8];
        #pragma unroll
        for (int mf = 0; mf < 4; ++mf)
            #pragma unroll
            for (int nf = 0; nf < 8; ++nf) acc2[mf][nf] = (f32x4)0.0f;

        #pragma unroll
        for (int ks = 0; ks < 4; ++ks) {
            int k0 = ks * 32 + g * 8;
            bf16x8 a[4], b[8];
            #pragma unroll
            for (int mf = 0; mf < 4; ++mf) {
                int h = wv * 64 + mf * 16 + lr;
                a[mf] = ld_frag_g(&smem[h * 128 + (k0 ^ ((h & 7) << 3))]);
            }
            #pragma unroll
            for (int nf = 0; nf < 8; ++nf) {
                int w = nh * 128 + nf * 16 + lr;
                b[nf] = ld_frag_g(B2T + w * 128 + k0);
            }
            #pragma unroll
            for (int mf = 0; mf < 4; ++mf)
                #pragma unroll
                for (int nf = 0; nf < 8; ++nf)
                    acc2[mf][nf] = __builtin_amdgcn_mfma_f32_16x16x32_bf16(
                                       a[mf], b[nf], acc2[mf][nf], 0, 0, 0);
        }
        #pragma unroll
        for (int mf = 0; mf < 4; ++mf)
            #pragma unroll
            for (int rg = 0; rg < 4; ++rg) {
                int h = wv * 64 + mf * 16 + g * 4 + rg;
                float* row = outp + h * 256 + nh * 128 + lr;
                #pragma unroll
                for (int nf = 0; nf < 8; ++nf)
                    row[nf * 16] = acc2[mf][nf][rg] * scale + bias;
            }
    }
}

extern "C" void kernel_launch(void* const* d_in, const int* in_sizes, int n_in,
                              void* d_out, int out_size, void* d_ws, size_t ws_size,
                              hipStream_t stream) {
    const float* x          = (const float*)d_in[0];
    const int*   q_real     = (const int*)  d_in[1];
    const int*   q_imag     = (const int*)  d_in[2];
    const int*   q_bias     = (const int*)  d_in[3];
    const float* scale_real = (const float*)d_in[4];
    const float* min_real   = (const float*)d_in[5];
    const float* scale_imag = (const float*)d_in[6];
    const float* min_imag   = (const float*)d_in[7];
    const float* b_scale    = (const float*)d_in[8];
    const float* b_min      = (const float*)d_in[9];
    float* out = (float*)d_out;

    float* ws = (float*)d_ws;
    unsigned short* A1tab = (unsigned short*)(ws);
    unsigned short* B2T   = (unsigned short*)(ws + 16384);
    unsigned short* B1fT  = (unsigned short*)(ws + 32768);
    unsigned short* A2f   = (unsigned short*)(ws + 49152);
    float*          Xws   = (float*)   (ws + 81920);
    unsigned*       Ybws  = (unsigned*)(ws + 81920 + 8388608);

    build_all_tables<<<512, 256, 0, stream>>>(A1tab, B2T, B1fT, A2f);
    fwd_mfma<<<NB * NCIN, 512, 0, stream>>>(x, B1fT, A2f, Xws);
    mix_kernel<<<dim3(64, 8), 256, 0, stream>>>(Xws, q_real, q_imag,
                                                scale_real, min_real,
                                                scale_imag, min_imag, Ybws);
    inv_mfma<<<NB * NCOUT, 256, 0, stream>>>(Ybws, A1tab, B2T,
                                             q_bias, b_scale, b_min, out);
}